// Round 12
// baseline (211.412 us; speedup 1.0000x reference)
//
#include <hip/hip_runtime.h>

constexpr int TPB   = 256;    // generic block
constexpr int NMAX  = 16384;  // fast-path cap (node ids fit 20 bits, rloc 6 bits)
constexpr int CHUNK = 2048;   // edges per k_p1 block
constexpr int GBMAX = 1024;   // fast-path cap on p1 grid

// edge_index delivered as int32 [2][E] (validated R3 counters + R6 pass).

// ============ fast path: two-level bucket CSR build, coalesced writes ============
// bucket = node >> rsh (RN = 1<<rsh <= 64 nodes/bucket, NBe = ceil(N/RN) <= 256)
// Tables stored TRANSPOSED [k*GB + b] so column ops are contiguous.

// ---- p1: partition edge-endpoint entries into per-(block,bucket) runs in tmp ----
__global__ __launch_bounds__(1024) void k_p1(const int* __restrict__ ei,
    const float* __restrict__ ew, int E, int rsh, int NBe, int GB,
    int* __restrict__ bstartT, int* __restrict__ bcntT, int2* __restrict__ tmp) {
    __shared__ int cnt[256];
    __shared__ int curs[256];
    __shared__ int sc[256];
    __shared__ int2 stg[2 * CHUNK];   // 32 KB
    int tid = threadIdx.x;
    int b = blockIdx.x;
    int e0 = b * CHUNK;
    int e1 = min(E, e0 + CHUNK);
    if (tid < NBe) cnt[tid] = 0;
    __syncthreads();
    int ea = e0 + tid, ebg = e0 + 1024 + tid;
    int r0 = 0, c0 = 0, r1 = 0, c1 = 0, w0 = 0, w1 = 0;
    bool va = ea < e1, vb = ebg < e1;
    if (va) { r0 = ei[ea];  c0 = ei[E + ea];  w0 = __float_as_int(0.5f * ew[ea]); }
    if (vb) { r1 = ei[ebg]; c1 = ei[E + ebg]; w1 = __float_as_int(0.5f * ew[ebg]); }
    if (va) { atomicAdd(&cnt[r0 >> rsh], 1); atomicAdd(&cnt[c0 >> rsh], 1); }
    if (vb) { atomicAdd(&cnt[r1 >> rsh], 1); atomicAdd(&cnt[c1 >> rsh], 1); }
    __syncthreads();
    int myc = (tid < NBe) ? cnt[tid] : 0;
    if (tid < NBe) sc[tid] = myc;
    __syncthreads();
    for (int off = 1; off < NBe; off <<= 1) {
        int v = 0;
        if (tid < NBe && tid >= off) v = sc[tid - off];
        __syncthreads();
        if (tid < NBe) sc[tid] += v;
        __syncthreads();
    }
    if (tid < NBe) {
        int excl = sc[tid] - myc;
        curs[tid] = excl;
        bstartT[tid * GB + b] = 2 * e0 + excl;   // transposed
        bcntT[tid * GB + b] = myc;
    }
    __syncthreads();
    int mask = (1 << rsh) - 1;
    if (va) {
        int p = atomicAdd(&curs[r0 >> rsh], 1);
        stg[p] = make_int2(((r0 & mask) << 20) | c0, w0);
        p = atomicAdd(&curs[c0 >> rsh], 1);
        stg[p] = make_int2(((c0 & mask) << 20) | r0, w0);
    }
    if (vb) {
        int p = atomicAdd(&curs[r1 >> rsh], 1);
        stg[p] = make_int2(((r1 & mask) << 20) | c1, w1);
        p = atomicAdd(&curs[c1 >> rsh], 1);
        stg[p] = make_int2(((c1 & mask) << 20) | r1, w1);
    }
    __syncthreads();
    int tot = 2 * (e1 - e0);
    for (int i = tid; i < tot; i += 1024) tmp[2 * e0 + i] = stg[i];  // coalesced burst
}

// ---- p2: per-bucket two-pass local sort (fused colsum + scan) -> CSR + rowptr + dis ----
__global__ __launch_bounds__(1024) void k_p2(const int2* __restrict__ tmp,
    const int* __restrict__ bstartT, const int* __restrict__ bcntT,
    int GB, int rsh, int N, int NBe, int M,
    int2* __restrict__ ent, int* __restrict__ rowptr, float* __restrict__ dis) {
    __shared__ int btl[256];
    __shared__ int sco[256];
    __shared__ int ncnt[256];
    __shared__ int nstart[256];
    __shared__ int ncur[256];
    __shared__ float wsum[256];
    int k = blockIdx.x;
    int tid = threadIdx.x;
    int RN = 1 << rsh;
    int n0 = k << rsh;
    // fused colsum: coalesced sweep of bcntT into LDS histogram (table is L2-resident)
    if (tid < 256) btl[tid] = 0;
    if (tid < RN) { ncnt[tid] = 0; wsum[tid] = 0.f; }
    __syncthreads();
    int totTab = NBe * GB;
    for (int i = tid; i < totTab; i += 1024) {
        atomicAdd(&btl[i / GB], bcntT[i]);
    }
    __syncthreads();
    // fused scan of btl -> eb
    int bt = (tid < 256) ? btl[tid] : 0;
    if (tid < 256) sco[tid] = bt;
    __syncthreads();
    for (int off = 1; off < 256; off <<= 1) {
        int v = 0;
        if (tid < 256 && tid >= off) v = sco[tid - off];
        __syncthreads();
        if (tid < 256) sco[tid] += v;
        __syncthreads();
    }
    int eb = sco[k] - btl[k];
    int grp = tid >> 2, sub = tid & 3;  // 4 threads per source block segment
    // Phase A: node-local histogram
    for (int b = grp; b < GB; b += 256) {
        int s = bstartT[k * GB + b];
        int l = bcntT[k * GB + b];
        for (int u = sub; u < l; u += 4) {
            int2 v = tmp[s + u];
            atomicAdd(&ncnt[v.x >> 20], 1);
        }
    }
    __syncthreads();
    int myc = (tid < RN) ? ncnt[tid] : 0;
    if (tid < RN) nstart[tid] = myc;
    __syncthreads();
    for (int off = 1; off < RN; off <<= 1) {
        int v = 0;
        if (tid < RN && tid >= off) v = nstart[tid - off];
        __syncthreads();
        if (tid < RN) nstart[tid] += v;
        __syncthreads();
    }
    if (tid < RN) { nstart[tid] -= myc; ncur[tid] = nstart[tid]; }
    __syncthreads();
    // Phase B: scatter into bucket's contiguous CSR region + weight sums
    for (int b = grp; b < GB; b += 256) {
        int s = bstartT[k * GB + b];
        int l = bcntT[k * GB + b];
        for (int u = sub; u < l; u += 4) {
            int2 v = tmp[s + u];
            int rl = v.x >> 20;
            int cc = v.x & 0xFFFFF;
            int p = atomicAdd(&ncur[rl], 1);
            ent[eb + p] = make_int2(cc, v.y);
            atomicAdd(&wsum[rl], __int_as_float(v.y));  // LDS float atomic
        }
    }
    __syncthreads();
    if (tid < RN && n0 + tid < N) {
        rowptr[n0 + tid] = eb + nstart[tid];
        dis[n0 + tid] = rsqrtf(1.f + wsum[tid]);
    }
    if (k == 0 && tid == 0) rowptr[N] = M;
}

// ============ fallback path: global-atomic prep ============
__global__ void k_init_fb(float* deg, int* counts, int N) {
    int i = blockIdx.x * TPB + threadIdx.x;
    if (i < N) { deg[i] = 1.0f; counts[i] = 0; }
}
__global__ void k_deg_cnt_fb(const int* __restrict__ ei, const float* __restrict__ ew,
                             float* deg, int* counts, int E) {
    int e = blockIdx.x * TPB + threadIdx.x;
    if (e >= E) return;
    int r = ei[e], c = ei[E + e];
    float hw = 0.5f * ew[e];
    unsafeAtomicAdd(&deg[r], hw);
    unsafeAtomicAdd(&deg[c], hw);
    atomicAdd(&counts[r], 1);
    atomicAdd(&counts[c], 1);
}
__global__ void k_rsqrt_fb(float* degdis, int N) {
    int i = blockIdx.x * TPB + threadIdx.x;
    if (i < N) {
        float d = degdis[i];
        degdis[i] = d > 0.f ? rsqrtf(d) : 0.f;
    }
}
__global__ void k_scan_fb(const int* __restrict__ counts, int* __restrict__ rowptr,
                          int* __restrict__ cursor, int N) {
    __shared__ int partial[TPB];
    int tid = threadIdx.x;
    int chunk = (N + TPB - 1) / TPB;
    int begin = tid * chunk;
    int end = begin + chunk; if (end > N) end = N;
    int s = 0;
    for (int i = begin; i < end; ++i) s += counts[i];
    partial[tid] = s;
    __syncthreads();
    for (int off = 1; off < TPB; off <<= 1) {
        int v = partial[tid];
        int add = (tid >= off) ? partial[tid - off] : 0;
        __syncthreads();
        partial[tid] = v + add;
        __syncthreads();
    }
    int base = (tid == 0) ? 0 : partial[tid - 1];
    for (int i = begin; i < end; ++i) {
        rowptr[i] = base; cursor[i] = base;
        base += counts[i];
    }
    if (tid == TPB - 1) rowptr[N] = base;
}
__global__ void k_fill_fb(const int* __restrict__ ei, const float* __restrict__ ew,
                          int* cursor, int2* __restrict__ ent, int E) {
    int e = blockIdx.x * TPB + threadIdx.x;
    if (e >= E) return;
    int r = ei[e], c = ei[E + e];
    int hw = __float_as_int(0.5f * ew[e]);
    int p1 = atomicAdd(&cursor[r], 1);
    ent[p1] = make_int2(c, hw);
    int p2 = atomicAdd(&cursor[c], 1);
    ent[p2] = make_int2(r, hw);
}

// ---------------- Z1[N,64] = dis .* (X[N,64] @ W1[64,64]) ----------------
__global__ void k_gemm1(const float* __restrict__ X, const float* __restrict__ W,
                        const float* __restrict__ dis, float* __restrict__ Z, int N) {
    __shared__ float Wl[64 * 64];
    int tid = threadIdx.x;
    #pragma unroll
    for (int i = tid; i < 4096; i += TPB) Wl[i] = W[i];
    __syncthreads();
    int row = blockIdx.x * 4 + (tid >> 6);
    int f = tid & 63;
    if (row >= N) return;
    const float* xr = X + row * 64;
    float s = 0.f;
    #pragma unroll
    for (int k = 0; k < 64; ++k) s = fmaf(xr[k], Wl[k * 64 + f], s);
    Z[row * 64 + f] = dis[row] * s;
}

// ---- layer-1 gather + FUSED layer-2 GEMM epilogue ----
// One node per wave (D=64). Gather loop as proven (UN=16 deep batches). After
// relu, H row lives one-feature-per-lane; fused H@W2 via 16 shuffles + 16 FMA
// per lane, butterfly-reduced over lane bits 4..5; lanes 0..15 write Z2.
__global__ void k_gatherL1(const float* __restrict__ Z, const int* __restrict__ rowptr,
                           const long long* __restrict__ entq, const float* __restrict__ dis,
                           const float* __restrict__ b1, const float* __restrict__ W2,
                           float* __restrict__ Z2, int N) {
    constexpr int UN = 16;
    __shared__ float W2s[64 * 16];
    int tid = threadIdx.x;
    #pragma unroll
    for (int i = tid; i < 1024; i += TPB) W2s[i] = W2[i];
    __syncthreads();
    int node = blockIdx.x * 4 + (tid >> 6);
    int f = tid & 63;     // lane id == feature (1 node per wave)
    if (node >= N) return;
    int j0 = rowptr[node], j1 = rowptr[node + 1];
    float acc = Z[node * 64 + f];
    long long cur = 0;
    if (j0 < j1) cur = __builtin_nontemporal_load(entq + j0 + f);  // ent padded by 64
    for (int jb = j0; jb < j1; jb += 64) {
        long long nxt = cur;
        if (jb + 64 < j1) nxt = __builtin_nontemporal_load(entq + jb + 64 + f);
        int ex = (int)cur;
        float ey = __int_as_float((int)(cur >> 32));
        int cnt = j1 - jb; if (cnt > 64) cnt = 64;
        int k = 0;
        for (; k + UN <= cnt; k += UN) {
            int n[UN]; float w[UN], z[UN];
            #pragma unroll
            for (int u = 0; u < UN; ++u) {
                n[u] = __shfl(ex, k + u);
                w[u] = __shfl(ey, k + u);
            }
            #pragma unroll
            for (int u = 0; u < UN; ++u) z[u] = Z[n[u] * 64 + f];  // 16 rows in flight
            #pragma unroll
            for (int u = 0; u < UN; ++u) acc = fmaf(w[u], z[u], acc);
        }
        for (; k < cnt; ++k) {
            int n0 = __shfl(ex, k);
            float w0 = __shfl(ey, k);
            acc = fmaf(w0, Z[n0 * 64 + f], acc);
        }
        cur = nxt;
    }
    float h = fmaf(dis[node], acc, b1[f]);
    h = h > 0.f ? h : 0.f;                 // H[node][f], one per lane
    // fused: Y2[g] = sum_f H[f] * W2[f][g]; lane l handles g=l&15, f-range (l>>4)*16..+16
    int g = f & 15, seg = f >> 4;
    float p = 0.f;
    #pragma unroll
    for (int i = 0; i < 16; ++i) {
        int ff = seg * 16 + i;
        float hv = __shfl(h, ff);
        p = fmaf(hv, W2s[ff * 16 + g], p);
    }
    p += __shfl_xor(p, 16);
    p += __shfl_xor(p, 32);
    if (seg == 0) Z2[node * 16 + g] = dis[node] * p;
}

// ---- layer-2 gather: scalar lanes (16/node), pipelined tiles, 16-deep batches ----
template <int D, bool RELU>
__global__ void k_gather(const float* __restrict__ Z, const int* __restrict__ rowptr,
                         const long long* __restrict__ entq, const float* __restrict__ dis,
                         const float* __restrict__ bias, float* __restrict__ out, int N) {
    constexpr int NPB = TPB / D;
    constexpr int UN = 16;
    int node = blockIdx.x * NPB + threadIdx.x / D;
    int f = threadIdx.x % D;
    int lane = threadIdx.x & 63;
    int base = lane & ~(D - 1);
    if (node >= N) return;
    int j0 = rowptr[node], j1 = rowptr[node + 1];
    float acc = Z[node * D + f];
    long long cur = 0;
    if (j0 < j1) cur = __builtin_nontemporal_load(entq + j0 + f);  // ent padded by 64
    for (int jb = j0; jb < j1; jb += D) {
        long long nxt = cur;
        if (jb + D < j1) nxt = __builtin_nontemporal_load(entq + jb + D + f);
        int ex = (int)cur;
        float ey = __int_as_float((int)(cur >> 32));
        int cnt = j1 - jb; if (cnt > D) cnt = D;
        int k = 0;
        for (; k + UN <= cnt; k += UN) {
            int n[UN]; float w[UN], z[UN];
            #pragma unroll
            for (int u = 0; u < UN; ++u) {
                n[u] = __shfl(ex, base + k + u);
                w[u] = __shfl(ey, base + k + u);
            }
            #pragma unroll
            for (int u = 0; u < UN; ++u) z[u] = Z[n[u] * D + f];
            #pragma unroll
            for (int u = 0; u < UN; ++u) acc = fmaf(w[u], z[u], acc);
        }
        for (; k < cnt; ++k) {
            int n0 = __shfl(ex, base + k);
            float w0 = __shfl(ey, base + k);
            acc = fmaf(w0, Z[n0 * D + f], acc);
        }
        cur = nxt;
    }
    float v = fmaf(dis[node], acc, bias[f]);
    if (RELU) v = v > 0.f ? v : 0.f;
    out[node * D + f] = v;
}

extern "C" void kernel_launch(void* const* d_in, const int* in_sizes, int n_in,
                              void* d_out, int out_size, void* d_ws, size_t ws_size,
                              hipStream_t stream) {
    const float* x  = (const float*)d_in[0];
    const float* W1 = (const float*)d_in[1];
    const float* b1 = (const float*)d_in[2];
    const float* W2 = (const float*)d_in[3];
    const float* b2 = (const float*)d_in[4];
    const float* ew = (const float*)d_in[5];
    const int*   ei = (const int*)d_in[6];   // int32 layout (validated)

    const int N = in_sizes[0] / 64;   // 16384
    const int E = in_sizes[5];        // 524288
    const int M = 2 * E;              // CSR entries

    // bucket geometry: RN = pow2 <= 64, NBe = ceil(N/RN) <= 256
    int rsh = 0;
    while ((256 << rsh) < N) ++rsh;
    const int NBe = (N + (1 << rsh) - 1) >> rsh;
    const int GB  = (E + CHUNK - 1) / CHUNK;

    char* ws = (char*)d_ws;
    size_t off = 0;
    auto alloc = [&](size_t bytes) -> void* {
        void* p = ws + off;
        off += (bytes + 255) & ~(size_t)255;
        return p;
    };
    float* dis     = (float*)alloc((size_t)N * 4);
    int*   counts  = (int*)alloc((size_t)N * 4);          // fallback only
    int*   rowptr  = (int*)alloc(((size_t)N + 1) * 4);
    int*   cursor  = (int*)alloc((size_t)N * 4);          // fallback only
    int2*  ent     = (int2*)alloc(((size_t)M + 64) * 8);  // +64 pad: gather tile prefetch
    int*   bstartT = (int*)alloc((size_t)GB * NBe * 4);   // [k*GB + b]
    int*   bcntT   = (int*)alloc((size_t)GB * NBe * 4);   // [k*GB + b]
    float* Z1      = (float*)alloc((size_t)N * 64 * 4);   // tmp aliases Z1+scratch (8 MB)
    float* scratch = (float*)alloc((size_t)N * 64 * 4);   // second half of tmp region
    float* Z2      = (float*)alloc((size_t)N * 16 * 4);
    (void)ws_size; (void)n_in; (void)out_size; (void)scratch;

    // tmp[M] int2 aliases Z1+scratch (consumed by k_p2 before k_gemm1 writes Z1)
    int2* tmp = (int2*)Z1;

    float* out = (float*)d_out;

    // fast path requires tmp (16E bytes) to fit inside Z1+scratch (512N bytes)
    if (N <= NMAX && GB <= GBMAX && (size_t)16 * E <= (size_t)512 * N) {
        k_p1<<<GB, 1024, 0, stream>>>(ei, ew, E, rsh, NBe, GB, bstartT, bcntT, tmp);
        k_p2<<<NBe, 1024, 0, stream>>>(tmp, bstartT, bcntT, GB, rsh, N, NBe, M,
                                       ent, rowptr, dis);
    } else {
        k_init_fb<<<(N + TPB - 1) / TPB, TPB, 0, stream>>>(dis, counts, N);
        k_deg_cnt_fb<<<(E + TPB - 1) / TPB, TPB, 0, stream>>>(ei, ew, dis, counts, E);
        k_rsqrt_fb<<<(N + TPB - 1) / TPB, TPB, 0, stream>>>(dis, N);
        k_scan_fb<<<1, TPB, 0, stream>>>(counts, rowptr, cursor, N);
        k_fill_fb<<<(E + TPB - 1) / TPB, TPB, 0, stream>>>(ei, ew, cursor, ent, E);
    }

    // layer 1: Z1 = dis.*(X@W1); then gather + fused layer-2 GEMM -> Z2
    k_gemm1<<<(N + 3) / 4, TPB, 0, stream>>>(x, W1, dis, Z1, N);
    k_gatherL1<<<(N + 3) / 4, TPB, 0, stream>>>(Z1, rowptr, (const long long*)ent,
                                                dis, b1, W2, Z2, N);
    // layer 2 gather: out = dis.*(gather Z2) + b2   (NPB=16 -> grid (N+15)/16)
    k_gather<16, false><<<(N + 15) / 16, TPB, 0, stream>>>(Z2, rowptr, (const long long*)ent,
                                                           dis, b2, out, N);
}

// Round 13
// 157.600 us; speedup vs baseline: 1.3414x; 1.3414x over previous
//
#include <hip/hip_runtime.h>

constexpr int TPB   = 256;    // generic block
constexpr int NMAX  = 16384;  // fast-path cap (node ids fit 20 bits, rloc 6 bits)
constexpr int CHUNK = 2048;   // edges per k_p1 block
constexpr int GBMAX = 1024;   // fast-path cap on p1 grid

// edge_index delivered as int32 [2][E] (validated R3 counters + R6 pass).

// ============ fast path: two-level bucket CSR build, coalesced writes ============
// bucket = node >> rsh (RN = 1<<rsh <= 64 nodes/bucket, NBe = ceil(N/RN) <= 256)
// Tables stored TRANSPOSED [k*GB + b] so column ops are contiguous.

// ---- p1: partition edge-endpoint entries into per-(block,bucket) runs in tmp ----
__global__ __launch_bounds__(1024) void k_p1(const int* __restrict__ ei,
    const float* __restrict__ ew, int E, int rsh, int NBe, int GB,
    int* __restrict__ bstartT, int* __restrict__ bcntT, int2* __restrict__ tmp) {
    __shared__ int cnt[256];
    __shared__ int curs[256];
    __shared__ int sc[256];
    __shared__ int2 stg[2 * CHUNK];   // 32 KB
    int tid = threadIdx.x;
    int b = blockIdx.x;
    int e0 = b * CHUNK;
    int e1 = min(E, e0 + CHUNK);
    if (tid < NBe) cnt[tid] = 0;
    __syncthreads();
    int ea = e0 + tid, ebg = e0 + 1024 + tid;
    int r0 = 0, c0 = 0, r1 = 0, c1 = 0, w0 = 0, w1 = 0;
    bool va = ea < e1, vb = ebg < e1;
    if (va) { r0 = ei[ea];  c0 = ei[E + ea];  w0 = __float_as_int(0.5f * ew[ea]); }
    if (vb) { r1 = ei[ebg]; c1 = ei[E + ebg]; w1 = __float_as_int(0.5f * ew[ebg]); }
    if (va) { atomicAdd(&cnt[r0 >> rsh], 1); atomicAdd(&cnt[c0 >> rsh], 1); }
    if (vb) { atomicAdd(&cnt[r1 >> rsh], 1); atomicAdd(&cnt[c1 >> rsh], 1); }
    __syncthreads();
    int myc = (tid < NBe) ? cnt[tid] : 0;
    if (tid < NBe) sc[tid] = myc;
    __syncthreads();
    for (int off = 1; off < NBe; off <<= 1) {
        int v = 0;
        if (tid < NBe && tid >= off) v = sc[tid - off];
        __syncthreads();
        if (tid < NBe) sc[tid] += v;
        __syncthreads();
    }
    if (tid < NBe) {
        int excl = sc[tid] - myc;
        curs[tid] = excl;
        bstartT[tid * GB + b] = 2 * e0 + excl;   // transposed
        bcntT[tid * GB + b] = myc;
    }
    __syncthreads();
    int mask = (1 << rsh) - 1;
    if (va) {
        int p = atomicAdd(&curs[r0 >> rsh], 1);
        stg[p] = make_int2(((r0 & mask) << 20) | c0, w0);
        p = atomicAdd(&curs[c0 >> rsh], 1);
        stg[p] = make_int2(((c0 & mask) << 20) | r0, w0);
    }
    if (vb) {
        int p = atomicAdd(&curs[r1 >> rsh], 1);
        stg[p] = make_int2(((r1 & mask) << 20) | c1, w1);
        p = atomicAdd(&curs[c1 >> rsh], 1);
        stg[p] = make_int2(((c1 & mask) << 20) | r1, w1);
    }
    __syncthreads();
    int tot = 2 * (e1 - e0);
    for (int i = tid; i < tot; i += 1024) tmp[2 * e0 + i] = stg[i];  // coalesced burst
}

// ---- colsum: one block per bucket, contiguous coalesced row sum -> btot[k] ----
// (Kept as a separate kernel: fusing it into p2 as an LDS-atomic sweep caused
//  64-way same-address LDS serialization — R12: 1.6e7 bank conflicts, +52 µs.)
__global__ void k_colsum(const int* __restrict__ bcntT, int GB,
                         int* __restrict__ btot) {
    __shared__ int red[TPB / 64];
    int k = blockIdx.x;
    int s = 0;
    for (int b = threadIdx.x; b < GB; b += TPB) s += bcntT[k * GB + b];
    #pragma unroll
    for (int off = 32; off; off >>= 1) s += __shfl_down(s, off, 64);
    int wv = threadIdx.x >> 6;
    if ((threadIdx.x & 63) == 0) red[wv] = s;
    __syncthreads();
    if (threadIdx.x == 0) {
        int t = 0;
        for (int w = 0; w < TPB / 64; ++w) t += red[w];
        btot[k] = t;
    }
}

// ---- p2: per-bucket two-pass local sort (fused btot scan) -> CSR + rowptr + dis ----
__global__ __launch_bounds__(1024) void k_p2(const int2* __restrict__ tmp,
    const int* __restrict__ bstartT, const int* __restrict__ bcntT,
    const int* __restrict__ btot, int GB, int rsh, int N, int NBe, int M,
    int2* __restrict__ ent, int* __restrict__ rowptr, float* __restrict__ dis) {
    __shared__ int sco[256];
    __shared__ int ncnt[256];
    __shared__ int nstart[256];
    __shared__ int ncur[256];
    __shared__ float wsum[256];
    int k = blockIdx.x;
    int tid = threadIdx.x;
    int RN = 1 << rsh;
    int n0 = k << rsh;
    // fused: exclusive scan of btot -> eb (1 KB, each block does it locally)
    int bt = (tid < NBe) ? btot[tid] : 0;
    if (tid < 256) sco[tid] = bt;
    if (tid < RN) { ncnt[tid] = 0; wsum[tid] = 0.f; }
    __syncthreads();
    for (int off = 1; off < 256; off <<= 1) {
        int v = 0;
        if (tid < 256 && tid >= off) v = sco[tid - off];
        __syncthreads();
        if (tid < 256) sco[tid] += v;
        __syncthreads();
    }
    int eb = sco[k] - btot[k];
    int grp = tid >> 2, sub = tid & 3;  // 4 threads per source block segment
    // Phase A: node-local histogram
    for (int b = grp; b < GB; b += 256) {
        int s = bstartT[k * GB + b];
        int l = bcntT[k * GB + b];
        for (int u = sub; u < l; u += 4) {
            int2 v = tmp[s + u];
            atomicAdd(&ncnt[v.x >> 20], 1);
        }
    }
    __syncthreads();
    int myc = (tid < RN) ? ncnt[tid] : 0;
    if (tid < RN) nstart[tid] = myc;
    __syncthreads();
    for (int off = 1; off < RN; off <<= 1) {
        int v = 0;
        if (tid < RN && tid >= off) v = nstart[tid - off];
        __syncthreads();
        if (tid < RN) nstart[tid] += v;
        __syncthreads();
    }
    if (tid < RN) { nstart[tid] -= myc; ncur[tid] = nstart[tid]; }
    __syncthreads();
    // Phase B: scatter into bucket's contiguous CSR region + weight sums
    for (int b = grp; b < GB; b += 256) {
        int s = bstartT[k * GB + b];
        int l = bcntT[k * GB + b];
        for (int u = sub; u < l; u += 4) {
            int2 v = tmp[s + u];
            int rl = v.x >> 20;
            int cc = v.x & 0xFFFFF;
            int p = atomicAdd(&ncur[rl], 1);
            ent[eb + p] = make_int2(cc, v.y);
            atomicAdd(&wsum[rl], __int_as_float(v.y));  // LDS float atomic
        }
    }
    __syncthreads();
    if (tid < RN && n0 + tid < N) {
        rowptr[n0 + tid] = eb + nstart[tid];
        dis[n0 + tid] = rsqrtf(1.f + wsum[tid]);
    }
    if (k == 0 && tid == 0) rowptr[N] = M;
}

// ============ fallback path: global-atomic prep ============
__global__ void k_init_fb(float* deg, int* counts, int N) {
    int i = blockIdx.x * TPB + threadIdx.x;
    if (i < N) { deg[i] = 1.0f; counts[i] = 0; }
}
__global__ void k_deg_cnt_fb(const int* __restrict__ ei, const float* __restrict__ ew,
                             float* deg, int* counts, int E) {
    int e = blockIdx.x * TPB + threadIdx.x;
    if (e >= E) return;
    int r = ei[e], c = ei[E + e];
    float hw = 0.5f * ew[e];
    unsafeAtomicAdd(&deg[r], hw);
    unsafeAtomicAdd(&deg[c], hw);
    atomicAdd(&counts[r], 1);
    atomicAdd(&counts[c], 1);
}
__global__ void k_rsqrt_fb(float* degdis, int N) {
    int i = blockIdx.x * TPB + threadIdx.x;
    if (i < N) {
        float d = degdis[i];
        degdis[i] = d > 0.f ? rsqrtf(d) : 0.f;
    }
}
__global__ void k_scan_fb(const int* __restrict__ counts, int* __restrict__ rowptr,
                          int* __restrict__ cursor, int N) {
    __shared__ int partial[TPB];
    int tid = threadIdx.x;
    int chunk = (N + TPB - 1) / TPB;
    int begin = tid * chunk;
    int end = begin + chunk; if (end > N) end = N;
    int s = 0;
    for (int i = begin; i < end; ++i) s += counts[i];
    partial[tid] = s;
    __syncthreads();
    for (int off = 1; off < TPB; off <<= 1) {
        int v = partial[tid];
        int add = (tid >= off) ? partial[tid - off] : 0;
        __syncthreads();
        partial[tid] = v + add;
        __syncthreads();
    }
    int base = (tid == 0) ? 0 : partial[tid - 1];
    for (int i = begin; i < end; ++i) {
        rowptr[i] = base; cursor[i] = base;
        base += counts[i];
    }
    if (tid == TPB - 1) rowptr[N] = base;
}
__global__ void k_fill_fb(const int* __restrict__ ei, const float* __restrict__ ew,
                          int* cursor, int2* __restrict__ ent, int E) {
    int e = blockIdx.x * TPB + threadIdx.x;
    if (e >= E) return;
    int r = ei[e], c = ei[E + e];
    int hw = __float_as_int(0.5f * ew[e]);
    int p1 = atomicAdd(&cursor[r], 1);
    ent[p1] = make_int2(c, hw);
    int p2 = atomicAdd(&cursor[c], 1);
    ent[p2] = make_int2(r, hw);
}

// ---------------- Z1[N,64] = dis .* (X[N,64] @ W1[64,64]) ----------------
__global__ void k_gemm1(const float* __restrict__ X, const float* __restrict__ W,
                        const float* __restrict__ dis, float* __restrict__ Z, int N) {
    __shared__ float Wl[64 * 64];
    int tid = threadIdx.x;
    #pragma unroll
    for (int i = tid; i < 4096; i += TPB) Wl[i] = W[i];
    __syncthreads();
    int row = blockIdx.x * 4 + (tid >> 6);
    int f = tid & 63;
    if (row >= N) return;
    const float* xr = X + row * 64;
    float s = 0.f;
    #pragma unroll
    for (int k = 0; k < 64; ++k) s = fmaf(xr[k], Wl[k * 64 + f], s);
    Z[row * 64 + f] = dis[row] * s;
}

// ---- layer-1 gather + FUSED layer-2 GEMM epilogue ----
// One node per wave (D=64). Gather loop as proven (UN=16 deep batches). After
// relu, H row lives one-feature-per-lane; fused H@W2 via 16 shuffles + 16 FMA
// per lane, butterfly-reduced over lane bits 4..5; lanes 0..15 write Z2.
__global__ void k_gatherL1(const float* __restrict__ Z, const int* __restrict__ rowptr,
                           const long long* __restrict__ entq, const float* __restrict__ dis,
                           const float* __restrict__ b1, const float* __restrict__ W2,
                           float* __restrict__ Z2, int N) {
    constexpr int UN = 16;
    __shared__ float W2s[64 * 16];
    int tid = threadIdx.x;
    #pragma unroll
    for (int i = tid; i < 1024; i += TPB) W2s[i] = W2[i];
    __syncthreads();
    int node = blockIdx.x * 4 + (tid >> 6);
    int f = tid & 63;     // lane id == feature (1 node per wave)
    if (node >= N) return;
    int j0 = rowptr[node], j1 = rowptr[node + 1];
    float acc = Z[node * 64 + f];
    long long cur = 0;
    if (j0 < j1) cur = __builtin_nontemporal_load(entq + j0 + f);  // ent padded by 64
    for (int jb = j0; jb < j1; jb += 64) {
        long long nxt = cur;
        if (jb + 64 < j1) nxt = __builtin_nontemporal_load(entq + jb + 64 + f);
        int ex = (int)cur;
        float ey = __int_as_float((int)(cur >> 32));
        int cnt = j1 - jb; if (cnt > 64) cnt = 64;
        int k = 0;
        for (; k + UN <= cnt; k += UN) {
            int n[UN]; float w[UN], z[UN];
            #pragma unroll
            for (int u = 0; u < UN; ++u) {
                n[u] = __shfl(ex, k + u);
                w[u] = __shfl(ey, k + u);
            }
            #pragma unroll
            for (int u = 0; u < UN; ++u) z[u] = Z[n[u] * 64 + f];  // 16 rows in flight
            #pragma unroll
            for (int u = 0; u < UN; ++u) acc = fmaf(w[u], z[u], acc);
        }
        for (; k < cnt; ++k) {
            int n0 = __shfl(ex, k);
            float w0 = __shfl(ey, k);
            acc = fmaf(w0, Z[n0 * 64 + f], acc);
        }
        cur = nxt;
    }
    float h = fmaf(dis[node], acc, b1[f]);
    h = h > 0.f ? h : 0.f;                 // H[node][f], one per lane
    // fused: Y2[g] = sum_f H[f] * W2[f][g]; lane l handles g=l&15, f-range (l>>4)*16..+16
    int g = f & 15, seg = f >> 4;
    float p = 0.f;
    #pragma unroll
    for (int i = 0; i < 16; ++i) {
        int ff = seg * 16 + i;
        float hv = __shfl(h, ff);
        p = fmaf(hv, W2s[ff * 16 + g], p);
    }
    p += __shfl_xor(p, 16);
    p += __shfl_xor(p, 32);
    if (seg == 0) Z2[node * 16 + g] = dis[node] * p;
}

// ---- layer-2 gather: scalar lanes (16/node), pipelined tiles, 16-deep batches ----
template <int D, bool RELU>
__global__ void k_gather(const float* __restrict__ Z, const int* __restrict__ rowptr,
                         const long long* __restrict__ entq, const float* __restrict__ dis,
                         const float* __restrict__ bias, float* __restrict__ out, int N) {
    constexpr int NPB = TPB / D;
    constexpr int UN = 16;
    int node = blockIdx.x * NPB + threadIdx.x / D;
    int f = threadIdx.x % D;
    int lane = threadIdx.x & 63;
    int base = lane & ~(D - 1);
    if (node >= N) return;
    int j0 = rowptr[node], j1 = rowptr[node + 1];
    float acc = Z[node * D + f];
    long long cur = 0;
    if (j0 < j1) cur = __builtin_nontemporal_load(entq + j0 + f);  // ent padded by 64
    for (int jb = j0; jb < j1; jb += D) {
        long long nxt = cur;
        if (jb + D < j1) nxt = __builtin_nontemporal_load(entq + jb + D + f);
        int ex = (int)cur;
        float ey = __int_as_float((int)(cur >> 32));
        int cnt = j1 - jb; if (cnt > D) cnt = D;
        int k = 0;
        for (; k + UN <= cnt; k += UN) {
            int n[UN]; float w[UN], z[UN];
            #pragma unroll
            for (int u = 0; u < UN; ++u) {
                n[u] = __shfl(ex, base + k + u);
                w[u] = __shfl(ey, base + k + u);
            }
            #pragma unroll
            for (int u = 0; u < UN; ++u) z[u] = Z[n[u] * D + f];
            #pragma unroll
            for (int u = 0; u < UN; ++u) acc = fmaf(w[u], z[u], acc);
        }
        for (; k < cnt; ++k) {
            int n0 = __shfl(ex, base + k);
            float w0 = __shfl(ey, base + k);
            acc = fmaf(w0, Z[n0 * D + f], acc);
        }
        cur = nxt;
    }
    float v = fmaf(dis[node], acc, bias[f]);
    if (RELU) v = v > 0.f ? v : 0.f;
    out[node * D + f] = v;
}

extern "C" void kernel_launch(void* const* d_in, const int* in_sizes, int n_in,
                              void* d_out, int out_size, void* d_ws, size_t ws_size,
                              hipStream_t stream) {
    const float* x  = (const float*)d_in[0];
    const float* W1 = (const float*)d_in[1];
    const float* b1 = (const float*)d_in[2];
    const float* W2 = (const float*)d_in[3];
    const float* b2 = (const float*)d_in[4];
    const float* ew = (const float*)d_in[5];
    const int*   ei = (const int*)d_in[6];   // int32 layout (validated)

    const int N = in_sizes[0] / 64;   // 16384
    const int E = in_sizes[5];        // 524288
    const int M = 2 * E;              // CSR entries

    // bucket geometry: RN = pow2 <= 64, NBe = ceil(N/RN) <= 256
    int rsh = 0;
    while ((256 << rsh) < N) ++rsh;
    const int NBe = (N + (1 << rsh) - 1) >> rsh;
    const int GB  = (E + CHUNK - 1) / CHUNK;

    char* ws = (char*)d_ws;
    size_t off = 0;
    auto alloc = [&](size_t bytes) -> void* {
        void* p = ws + off;
        off += (bytes + 255) & ~(size_t)255;
        return p;
    };
    float* dis     = (float*)alloc((size_t)N * 4);
    int*   counts  = (int*)alloc((size_t)N * 4);          // fallback only
    int*   rowptr  = (int*)alloc(((size_t)N + 1) * 4);
    int*   cursor  = (int*)alloc((size_t)N * 4);          // fallback only
    int2*  ent     = (int2*)alloc(((size_t)M + 64) * 8);  // +64 pad: gather tile prefetch
    int*   bstartT = (int*)alloc((size_t)GB * NBe * 4);   // [k*GB + b]
    int*   bcntT   = (int*)alloc((size_t)GB * NBe * 4);   // [k*GB + b]
    int*   btot    = (int*)alloc(((size_t)NBe + 1) * 4);
    float* Z1      = (float*)alloc((size_t)N * 64 * 4);   // tmp aliases Z1+scratch (8 MB)
    float* scratch = (float*)alloc((size_t)N * 64 * 4);   // second half of tmp region
    float* Z2      = (float*)alloc((size_t)N * 16 * 4);
    (void)ws_size; (void)n_in; (void)out_size; (void)scratch;

    // tmp[M] int2 aliases Z1+scratch (consumed by k_p2 before k_gemm1 writes Z1)
    int2* tmp = (int2*)Z1;

    float* out = (float*)d_out;

    // fast path requires tmp (16E bytes) to fit inside Z1+scratch (512N bytes)
    if (N <= NMAX && GB <= GBMAX && (size_t)16 * E <= (size_t)512 * N) {
        k_p1<<<GB, 1024, 0, stream>>>(ei, ew, E, rsh, NBe, GB, bstartT, bcntT, tmp);
        k_colsum<<<NBe, TPB, 0, stream>>>(bcntT, GB, btot);
        k_p2<<<NBe, 1024, 0, stream>>>(tmp, bstartT, bcntT, btot, GB, rsh, N, NBe, M,
                                       ent, rowptr, dis);
    } else {
        k_init_fb<<<(N + TPB - 1) / TPB, TPB, 0, stream>>>(dis, counts, N);
        k_deg_cnt_fb<<<(E + TPB - 1) / TPB, TPB, 0, stream>>>(ei, ew, dis, counts, E);
        k_rsqrt_fb<<<(N + TPB - 1) / TPB, TPB, 0, stream>>>(dis, N);
        k_scan_fb<<<1, TPB, 0, stream>>>(counts, rowptr, cursor, N);
        k_fill_fb<<<(E + TPB - 1) / TPB, TPB, 0, stream>>>(ei, ew, cursor, ent, E);
    }

    // layer 1: Z1 = dis.*(X@W1); then gather + fused layer-2 GEMM -> Z2
    k_gemm1<<<(N + 3) / 4, TPB, 0, stream>>>(x, W1, dis, Z1, N);
    k_gatherL1<<<(N + 3) / 4, TPB, 0, stream>>>(Z1, rowptr, (const long long*)ent,
                                                dis, b1, W2, Z2, N);
    // layer 2 gather: out = dis.*(gather Z2) + b2   (NPB=16 -> grid (N+15)/16)
    k_gather<16, false><<<(N + 15) / 16, TPB, 0, stream>>>(Z2, rowptr, (const long long*)ent,
                                                           dis, b2, out, N);
}